// Round 11
// baseline (475.601 us; speedup 1.0000x reference)
//
#include <hip/hip_runtime.h>
#include <cstdint>

#define NB 32
#define NBW 16
#define IC 2048
#define IK 16
#define OC 64
#define OD 32
#define ODF (OC*OD)          // 2048 flattened od
#define NCH 128              // i-chunks
#define CHUNK (IC/NCH)       // 16
#define PARTBLK (NBW*ODF)    // 32768 floats per slot
#define NSLOT (NCH*2)        // 256 wgs

typedef __fp16 h2 __attribute__((ext_vector_type(2)));
typedef __fp16 h8 __attribute__((ext_vector_type(8)));
typedef float  f4 __attribute__((ext_vector_type(4)));

__device__ __forceinline__ h2 pk2(float a, float b) {
#if __has_builtin(__builtin_amdgcn_cvt_pkrtz)
  return __builtin_amdgcn_cvt_pkrtz(a, b);
#else
  h2 r; r.x = (__fp16)a; r.y = (__fp16)b; return r;
#endif
}
__device__ __forceinline__ unsigned int bcu(h2 v){ return __builtin_bit_cast(unsigned int, v); }
__device__ __forceinline__ h8 bch8(uint4 u){ return __builtin_bit_cast(h8, u); }

__device__ __forceinline__ f4 mfma_16x16x32(h8 a, h8 b, f4 c) {
  return __builtin_amdgcn_mfma_f32_16x16x32_f16(a, b, c, 0, 0, 0);
}

// MFMA routing pass, phase-batched (R10 lesson: per-i softmax = 2 barriers/i
// + LDS s-RMW at 1 wg/CU -> 154us with everything <20% utilized).
// wg = 1024 thr (16 waves) covers all 128 od-tiles x 16 b; 2 twins per ci.
// ITER=0: pure GEMM, two i per MFMA (K=32), acc[8] in regs.
// ITER>0, per 8-i group:
//   P1: MFMA u for 8 i, dot with v, shuffle-reduce -> agr[8][64][17] LDS
//   P2: ONE batched softmax: 128 rows (i,b), 8 rows/wave -> c_s[8][16][68]
//   P3: re-MFMA u (MFMA is ~2% busy - recompute is free), acc[tt] += c*u in
//       REGISTERS (no s_lds tile). ii reversed for L2 reuse of phase-1 W.
// Barriers: 4 per group (was 17). LDS 74 KB -> 2 wg/CU.
template<int ITER>
__global__ __launch_bounds__(1024)
void caps_pass(const float* __restrict__ xg, const float* __restrict__ Wg,
               const float* __restrict__ vin, const float* __restrict__ binT,
               float* __restrict__ boutT, float* __restrict__ part)
{
  __shared__ uint4 x_h[8][2][16];                       // 4 KB packed-f16 x
  __shared__ float agr[(ITER==0)?1:(8*64*17)];          // 34 KB  [ii][o][b]
  __shared__ float c_s[(ITER==0)?1:(8*16*68)];          // 34 KB  [ii][b][o]

  const int t  = threadIdx.x;       // 0..1023
  const int w  = t >> 6;            // wave 0..15
  const int l  = t & 63;
  const int lb = l & 15;            // tile col (b) / A row (od)
  const int lg = l >> 4;            // lane group 0..3

  // bid%8 = XCD; twin pair (bh 0/1) of one ci lands on the same XCD's L2.
  const int bid  = blockIdx.x;
  const int slot = bid >> 3;        // 0..31
  const int bh   = slot & 1;
  const int ci   = (bid & 7) * 16 + (slot >> 1);   // 0..127
  const int i0   = ci * CHUNK;
  const int bg0  = bh * NBW;
  const f4 zf = {0.f, 0.f, 0.f, 0.f};

  f4 acc[8];
#pragma unroll
  for (int q = 0; q < 8; ++q) acc[q] = zf;

  for (int g8 = 0; g8 < CHUNK; g8 += 8) {
    if (g8) __syncthreads();        // x_h readers of prev group done
    if (t < 256) {                  // stage x[16 b][8 i][16 k] as f16
      const int si = t >> 5, kc = (t >> 4) & 1, sb = t & 15;
      const float* xp = &xg[((size_t)(bg0 + sb)*IC + (i0 + g8 + si))*IK + kc*8];
      const float4 xa = *(const float4*)xp;
      const float4 xb = *(const float4*)(xp + 4);
      uint4 u;
      u.x = bcu(pk2(xa.x, xa.y)); u.y = bcu(pk2(xa.z, xa.w));
      u.z = bcu(pk2(xb.x, xb.y)); u.w = bcu(pk2(xb.z, xb.w));
      x_h[si][kc][sb] = u;
    }
    __syncthreads();

    if (ITER == 0) {
#pragma unroll 1
      for (int p = 0; p < 4; ++p) {           // pair of i per MFMA (K=32)
        const int isel = lg >> 1, kc = lg & 1;
        const int il = p*2 + isel;            // group-local i
        const h8 B = bch8(x_h[il][kc][lb]);
        const size_t wbase = ((size_t)(i0 + g8 + il)*ODF + lb)*IK + kc*8;
#pragma unroll
        for (int tt = 0; tt < 8; ++tt) {
          const float* wp = &Wg[wbase + (size_t)((w*8 + tt)*16)*IK];
          const float4 wa = *(const float4*)wp;
          const float4 wb = *(const float4*)(wp + 4);
          uint4 au;
          au.x = bcu(pk2(wa.x, wa.y)); au.y = bcu(pk2(wa.z, wa.w));
          au.z = bcu(pk2(wb.x, wb.y)); au.w = bcu(pk2(wb.z, wb.w));
          acc[tt] = mfma_16x16x32(bch8(au), B, acc[tt]);
        }
      }
    } else {
      // ---- PHASE 1: agreements for 8 i ----
#pragma unroll 1
      for (int ii = 0; ii < 8; ++ii) {
        const int i = i0 + g8 + ii;
        uint4 bu = {0u,0u,0u,0u};
        if (lg < 2) bu = x_h[ii][lg][lb];     // real K half; rest zero-pad
        const h8 B = bch8(bu);
        float ap[4] = {0.f, 0.f, 0.f, 0.f};
#pragma unroll
        for (int tt = 0; tt < 8; ++tt) {
          uint4 au = {0u,0u,0u,0u};
          if (lg < 2) {
            const float* wp = &Wg[((size_t)i*ODF + (w*8+tt)*16 + lb)*IK + lg*8];
            const float4 wa = *(const float4*)wp;
            const float4 wb = *(const float4*)(wp + 4);
            au.x = bcu(pk2(wa.x, wa.y)); au.y = bcu(pk2(wa.z, wa.w));
            au.z = bcu(pk2(wb.x, wb.y)); au.w = bcu(pk2(wb.z, wb.w));
          }
          const f4 u = mfma_16x16x32(bch8(au), B, zf);
          const int o = w*4 + (tt >> 1);
          const float4 vv = *(const float4*)
            &vin[((size_t)(bg0 + lb)*OC + o)*OD + (tt & 1)*16 + lg*4];
          ap[tt >> 1] += u.x*vv.x + u.y*vv.y + u.z*vv.z + u.w*vv.w;
        }
#pragma unroll
        for (int q = 0; q < 4; ++q) {         // sum the 4 d-lane-groups
          float a = ap[q];
          a += __shfl_xor(a, 16);
          a += __shfl_xor(a, 32);
          if (l < 16) {
            const int o = w*4 + q;
            float bn = a;
            if (ITER == 2) bn += binT[((size_t)i*OC + o)*NB + bg0 + lb];
            if (ITER == 1) boutT[((size_t)i*OC + o)*NB + bg0 + lb] = bn;
            agr[(ii*64 + o)*17 + lb] = bn;
          }
        }
      }
      __syncthreads();
      // ---- PHASE 2: batched softmax, 128 rows, 8 rows per wave ----
#pragma unroll
      for (int r = 0; r < 8; ++r) {
        const int row = w*8 + r;
        const int si = row >> 4, b = row & 15;
        const float a = agr[(si*64 + l)*17 + b];   // o = l
        float m = a;
#pragma unroll
        for (int off = 1; off < 64; off <<= 1) m = fmaxf(m, __shfl_xor(m, off));
        const float e = __expf(a - m);
        float se = e;
#pragma unroll
        for (int off = 1; off < 64; off <<= 1) se += __shfl_xor(se, off);
        c_s[(si*16 + b)*68 + l] = e / se;
      }
      __syncthreads();
      // ---- PHASE 3: recompute u, accumulate s in regs (ii reversed: L2) ----
#pragma unroll 1
      for (int ii = 7; ii >= 0; --ii) {
        const int i = i0 + g8 + ii;
        uint4 bu = {0u,0u,0u,0u};
        if (lg < 2) bu = x_h[ii][lg][lb];
        const h8 B = bch8(bu);
#pragma unroll
        for (int tt = 0; tt < 8; ++tt) {
          uint4 au = {0u,0u,0u,0u};
          if (lg < 2) {
            const float* wp = &Wg[((size_t)i*ODF + (w*8+tt)*16 + lb)*IK + lg*8];
            const float4 wa = *(const float4*)wp;
            const float4 wb = *(const float4*)(wp + 4);
            au.x = bcu(pk2(wa.x, wa.y)); au.y = bcu(pk2(wa.z, wa.w));
            au.z = bcu(pk2(wb.x, wb.y)); au.w = bcu(pk2(wb.z, wb.w));
          }
          const f4 u = mfma_16x16x32(bch8(au), B, zf);
          const float cm = c_s[(ii*16 + lb)*68 + (w*4 + (tt >> 1))];
          acc[tt].x += cm*u.x; acc[tt].y += cm*u.y;
          acc[tt].z += cm*u.z; acc[tt].w += cm*u.w;
        }
      }
    }
  }

  // flush partial s from regs (cells owned per-thread)
  const float scale = (ITER == 0) ? (1.0f/64.0f) : 1.0f;
  float* pp = part + (size_t)(ci*2 + bh)*PARTBLK;
#pragma unroll
  for (int tt = 0; tt < 8; ++tt) {
    float4 st;
    st.x = acc[tt].x*scale; st.y = acc[tt].y*scale;
    st.z = acc[tt].z*scale; st.w = acc[tt].w*scale;
    *(float4*)&pp[(size_t)lb*ODF + (w*8 + tt)*16 + lg*4] = st;
  }
}

// Sum the 128 i-chunk partials (per b-half) and apply squash.
// One 64-thr block per (b,o): lanes 0..31 = d, halves split the ci range.
__global__ __launch_bounds__(64)
void caps_reduce(const float* __restrict__ part, float* __restrict__ vout)
{
  const int r  = blockIdx.x;           // b*OC + o
  const int b  = r >> 6, o = r & 63;
  const int bh = b >> 4, bl = b & 15;
  const int d  = threadIdx.x & 31;
  const int h  = threadIdx.x >> 5;
  const float* p = part + (size_t)bh*PARTBLK + (size_t)bl*ODF + o*OD + d;
  float s = 0.f;
#pragma unroll 4
  for (int q = 0; q < NCH/2; ++q)
    s += p[(size_t)((h*(NCH/2) + q)*2)*PARTBLK];
  s += __shfl_xor(s, 32);
  float n2 = s*s;
#pragma unroll
  for (int off = 1; off < 32; off <<= 1) n2 += __shfl_xor(n2, off);
  const float n = sqrtf(n2);
  const float f = n2 / ((1.f + n2)*(n + 1e-8f));   // squash, matches ref
  if (h == 0) vout[(size_t)r*OD + d] = s*f;
}

extern "C" void kernel_launch(void* const* d_in, const int* in_sizes, int n_in,
                              void* d_out, int out_size, void* d_ws, size_t ws_size,
                              hipStream_t stream)
{
  const float* xg = (const float*)d_in[0];
  const float* Wg = (const float*)d_in[1];
  float* out = (float*)d_out;

  const size_t part_bytes = (size_t)NSLOT*PARTBLK*sizeof(float);  // 32 MB
  const size_t bbuf_bytes = (size_t)IC*OC*NB*sizeof(float);       // 16 MB
  float* part = (float*)d_ws;
  float* bbuf = (float*)((char*)d_ws + part_bytes);
  float* vbuf = (float*)((char*)bbuf + bbuf_bytes);
  (void)ws_size;

  // iter 1: c = 1/64 exactly -> pure GEMM, acc in regs
  caps_pass<0><<<NSLOT, 1024, 0, stream>>>(xg, Wg, nullptr, nullptr, nullptr, part);
  caps_reduce<<<NB*OC, 64, 0, stream>>>(part, vbuf);
  // iter 2: A1 = u.v1, c = softmax(A1); store A1 (transposed [i][o][b])
  caps_pass<1><<<NSLOT, 1024, 0, stream>>>(xg, Wg, vbuf, nullptr, bbuf, part);
  caps_reduce<<<NB*OC, 64, 0, stream>>>(part, vbuf);
  // iter 3: c = softmax(A1 + u.v2)
  caps_pass<2><<<NSLOT, 1024, 0, stream>>>(xg, Wg, vbuf, bbuf, nullptr, part);
  caps_reduce<<<NB*OC, 64, 0, stream>>>(part, out);
}